// Round 6
// baseline (342.241 us; speedup 1.0000x reference)
//
#include <hip/hip_runtime.h>
#include <stdint.h>

#define D_DIM 128
#define NROW 8192
#define MROW 8192
#define OUT_LD 8192
#define LDP 136        // padded bf16 per LDS row (272 B stride -> 2-way max on b128 reads, free)
#define PANEL 1024     // out cols per XCD panel
#define CTILE 128      // out cols per Y tile
#define NT_PER_BLK (PANEL / CTILE)   // 8

typedef __bf16 bf16x8 __attribute__((ext_vector_type(8)));
typedef float f32x4 __attribute__((ext_vector_type(4)));
typedef unsigned short us8 __attribute__((ext_vector_type(8)));

// Fused: bf16 (RNE) conversion of X,Y into d_ws + exact f32 row norms.
__global__ __launch_bounds__(256) void rbf_prep(const float* __restrict__ X,
                                                const float* __restrict__ Y,
                                                float* __restrict__ nrm,
                                                unsigned short* __restrict__ Xb,
                                                unsigned short* __restrict__ Yb) {
    const int t = threadIdx.x;
    const int w = t >> 6, lane = t & 63;
    const int rid = blockIdx.x * 4 + w;
    const float* src;
    unsigned short* dst;
    if (rid < NROW) { src = X + (size_t)rid * D_DIM;          dst = Xb + (size_t)rid * D_DIM; }
    else            { src = Y + (size_t)(rid - NROW) * D_DIM; dst = Yb + (size_t)(rid - NROW) * D_DIM; }
    float2 v = *(const float2*)(src + 2 * lane);
    union { __bf16 h[2]; uint32_t u; } cv;
    cv.h[0] = (__bf16)v.x; cv.h[1] = (__bf16)v.y;
    *(uint32_t*)(dst + 2 * lane) = cv.u;
    float s = v.x * v.x + v.y * v.y;
    #pragma unroll
    for (int off = 32; off > 0; off >>= 1) s += __shfl_xor(s, off, 64);
    if (lane == 0) nrm[rid] = s;
}

// Panel-per-XCD GEMM-epilogue kernel.
//  b&7 = XCD = column panel (8 panels x 1024 cols); b>>3 = 128-row band.
//  All 64 blocks of a panel co-resident on one XCD -> Y panel (256 KB) L2-hot.
//  Wave-tile 64x64. X fragments in registers (loaded once); only Y staged in LDS.
//  mfma(A=Yfrag, B=Xfrag): D col(n)=l16 -> out row; row(m)=quad*4+r -> out col,
//  so each acc f32x4 = 4 consecutive out cols -> direct dwordx4 NT stores.
__global__ __launch_bounds__(256, 2) void rbf_band(const unsigned short* __restrict__ Xb,
                                                   const unsigned short* __restrict__ Yb,
                                                   const float* __restrict__ sigma,
                                                   const float* __restrict__ nrm,
                                                   float* __restrict__ out) {
    __shared__ __align__(16) unsigned short Ys[CTILE][LDP];   // 34816 B

    const int b = blockIdx.x;
    const int panel = b & 7;
    const int row0 = (b >> 3) * 128;          // X rows (out rows)
    const int pcol0 = panel * PANEL;          // panel base col

    const int t = threadIdx.x;
    const int w = t >> 6, ln = t & 63;
    const int quad = ln >> 4, l16 = ln & 15;
    const int wr = (w >> 1) * 64;             // wave's 64-row half
    const int wc = (w & 1) * 64;              // wave's 64-col half (within tile)

    // X fragments in registers: 4 row-frags x 4 k-steps, one us8 (16 B) each.
    // Wave reads its 64 rows fully (each row: 4 quads x 4 ks x 16 B = 256 B).
    bf16x8 xf[4][4];
    #pragma unroll
    for (int ti = 0; ti < 4; ++ti)
        #pragma unroll
        for (int ks = 0; ks < 4; ++ks)
            xf[ti][ks] = *(const bf16x8*)(Xb + (size_t)(row0 + wr + ti * 16 + l16) * D_DIM
                                          + ks * 32 + quad * 8);

    const float s2 = sigma[0] * sigma[0] + 1e-9f;
    const float cexp = -1.4426950408889634f / s2;   // exp(-d/s2) = exp2(d*cexp)
    const float c2 = -2.0f * cexp;

    float x2c[4];
    #pragma unroll
    for (int ti = 0; ti < 4; ++ti)
        x2c[ti] = nrm[row0 + wr + ti * 16 + l16] * cexp;

    for (int ct = 0; ct < NT_PER_BLK; ++ct) {
        const int col0 = pcol0 + ct * CTILE;
        if (ct > 0) __syncthreads();          // prior tile's reads done before restage

        // Stage Y tile: 128 rows x 128 k bf16 = 32 KB, 16 B per thread-iter.
        #pragma unroll
        for (int i = 0; i < 8; ++i) {
            int f = t + 256 * i;
            int r = f >> 4;                   // 0..127
            int k = (f & 15) * 8;             // 0..120
            *(us8*)(&Ys[r][k]) = *(const us8*)(Yb + (size_t)(col0 + r) * D_DIM + k);
        }
        __syncthreads();

        f32x4 acc[4][4] = {};   // [ti = out-row frag][tj = out-col frag]
        #pragma unroll
        for (int ks = 0; ks < 4; ++ks) {
            const int k = ks * 32 + quad * 8;
            bf16x8 yf[4];
            #pragma unroll
            for (int tj = 0; tj < 4; ++tj)
                yf[tj] = *(const bf16x8*)(&Ys[wc + tj * 16 + l16][k]);
            #pragma unroll
            for (int ti = 0; ti < 4; ++ti)
                #pragma unroll
                for (int tj = 0; tj < 4; ++tj)
                    acc[ti][tj] = __builtin_amdgcn_mfma_f32_16x16x32_bf16(yf[tj], xf[ti][ks], acc[ti][tj], 0, 0, 0);
        }

        // Epilogue: exp2( c2*acc + (x2c + y2c) ), 2 VALU + exp per element.
        #pragma unroll
        for (int ti = 0; ti < 4; ++ti) {
            const size_t grow = (size_t)(row0 + wr + ti * 16 + l16);
            #pragma unroll
            for (int tj = 0; tj < 4; ++tj) {
                const int colb = col0 + wc + tj * 16 + quad * 4;
                f32x4 y2v = *(const f32x4*)(nrm + NROW + colb);
                f32x4 v;
                #pragma unroll
                for (int r = 0; r < 4; ++r)
                    v[r] = __builtin_amdgcn_exp2f(fmaf(c2, acc[ti][tj][r], x2c[ti] + y2v[r] * cexp));
                __builtin_nontemporal_store(v, (f32x4*)(out + grow * OUT_LD + colb));
            }
        }
    }
}

extern "C" void kernel_launch(void* const* d_in, const int* in_sizes, int n_in,
                              void* d_out, int out_size, void* d_ws, size_t ws_size,
                              hipStream_t stream) {
    const float* X = (const float*)d_in[0];
    const float* Y = (const float*)d_in[1];
    const float* sigma = (const float*)d_in[2];
    float* nrm = (float*)d_ws;                                   // 64 KB
    unsigned short* Xb = (unsigned short*)d_ws + 32768;          // 2 MB bf16 X
    unsigned short* Yb = Xb + (size_t)NROW * D_DIM;              // 2 MB bf16 Y
    float* out = (float*)d_out;

    rbf_prep<<<(NROW + MROW) / 4, 256, 0, stream>>>(X, Y, nrm, Xb, Yb);
    rbf_band<<<(NROW / 128) * 8, 256, 0, stream>>>(Xb, Yb, sigma, nrm, out);
}